// Round 1
// baseline (77951.483 us; speedup 1.0000x reference)
//
#include <hip/hip_runtime.h>
#include <hip/hip_bf16.h>

typedef unsigned int uint32;
typedef unsigned short u16;

#define H    768
#define H2   1536
#define H3   2304
#define H6   4608
#define BB   8
#define SS   128
#define GG   1024
#define NWG  64
#define NT   256
#define INVSCALE 0.036084391824351615f

struct IN {
  const int *chat_ids, *speaker_info, *inputs;
  const float *emb, *d_wih, *d_whh, *d_bih, *d_bhh;
  const float *g_wih, *g_whh, *g_bih, *g_bhh;
  const float *s_wih, *s_whh, *s_bih, *s_bhh;
  const float *wq, *bq, *wk, *bk, *wv, *bv;
  const float *h0, *d_h0, *attn_h;
};

struct WS {
  int *flags1, *flags2;
  float *Mqk, *Gsum;
  float *cu, *vkq, *cb, *cvs, *ch0s, *cvg, *chg0, *ghs0;
  u16 *MsT, *MgT, *s_whhT, *g_whhT, *g_wihABT, *d_whhT;
  float *gi_d, *GIS;   // aliased region (gi_d dead before GIS is written)
  float *dialogue, *U, *cvec, *GIG, *gh_d;
  float *op_buf, *OPMS, *OPMG;
  float *gi_attn, *gh_s2, *gh_g2, *gig_w2, *gig_h, *scores_buf, *probs_buf;
  float *h_buf, *Wbuf, *AO;
  float *out_op, *out_spop;
};

__device__ inline float sigm(float x) { return 1.f / (1.f + expf(-x)); }

__device__ inline u16 f2bf(float v) {
  __hip_bfloat16 b = __float2bfloat16(v);
  return *reinterpret_cast<u16*>(&b);
}

// ---- device-scope grid barrier (64 WGs, all resident on 256 CUs) ----
__device__ inline void gbar(int* flags, int epoch, int& dead) {
  int bail = 0;
  __syncthreads();
  if (!dead && threadIdx.x < NWG) {
    __threadfence();  // release: flush this WG's stores to coherence point
    if (threadIdx.x == 0)
      __hip_atomic_store(&flags[blockIdx.x], epoch, __ATOMIC_RELAXED, __HIP_MEMORY_SCOPE_AGENT);
    int spins = 0;
    while (__hip_atomic_load(&flags[threadIdx.x], __ATOMIC_RELAXED, __HIP_MEMORY_SCOPE_AGENT) < epoch) {
      if (++spins > (1 << 21)) { bail = 1; break; }
    }
  }
  dead |= __syncthreads_or(bail);
  __threadfence();  // acquire: invalidate stale cached lines
  __syncthreads();
}

// ---- distributed matvec: out[n0..n0+128) += sum_a x[a]*W[a][n] ; W bf16 [K][ldw] ----
// 4-wave K-split, lane handles 2 adjacent outputs via one uint (2xbf16) load.
__device__ inline void mv128(const u16* W, int ldw, const float* x, int K, int n0,
                             float* out, const float* bias, float* red, int tid) {
  const uint32* Wp = (const uint32*)W;
  int l = tid & 63, wvn = tid >> 6;
  int kc = K >> 2;
  int kb = wvn * kc, ke = kb + kc;
  long step = ldw >> 1;
  const uint32* p = Wp + (long)kb * step + (n0 >> 1) + l;
  float a0 = 0.f, a1 = 0.f;
  for (int a = kb; a < ke; a++) {
    float xv = x[a];
    uint32 u = *p; p += step;
    a0 = fmaf(xv, __uint_as_float(u << 16), a0);
    a1 = fmaf(xv, __uint_as_float(u & 0xffff0000u), a1);
  }
  __syncthreads();
  red[wvn * 128 + 2 * l] = a0; red[wvn * 128 + 2 * l + 1] = a1;
  __syncthreads();
  if (tid < 128) {
    float v = red[tid] + red[128 + tid] + red[256 + tid] + red[384 + tid];
    out[n0 + tid] = v + (bias ? bias[n0 + tid] : 0.f);
  }
}

// ---- fused task: compute OPMS/OPMG row (s-1) from local op, store it, and the
//      probability-weighted sum over rows 0..s-1 into OUT (+const vec). K = 768. ----
__device__ inline void wsum_task(const u16* MT, int ldm, const float* opc, float* ROWBUF,
                                 float* OUT, const float* CADD, const float* probs,
                                 int s, int n0, float* red, int tid) {
  const uint32* Wp = (const uint32*)MT;
  int l = tid & 63, wvn = tid >> 6;
  int kb = wvn * 192, ke = kb + 192;
  long step = ldm >> 1;
  const uint32* p = Wp + (long)kb * step + (n0 >> 1) + l;
  float a0 = 0.f, a1 = 0.f;
  for (int a = kb; a < ke; a++) {
    float xv = opc[a];
    uint32 u = *p; p += step;
    a0 = fmaf(xv, __uint_as_float(u << 16), a0);
    a1 = fmaf(xv, __uint_as_float(u & 0xffff0000u), a1);
  }
  float b0 = 0.f, b1 = 0.f;
  for (int j = wvn; j <= s - 2; j += 4) {
    float pj = probs[j];
    const float2* r2 = (const float2*)(ROWBUF + (long)j * ldm + n0);
    float2 v = r2[l];
    b0 = fmaf(pj, v.x, b0);
    b1 = fmaf(pj, v.y, b1);
  }
  __syncthreads();
  red[wvn * 128 + 2 * l] = a0; red[wvn * 128 + 2 * l + 1] = a1;
  __syncthreads();
  float row = 0.f;
  if (tid < 128) row = red[tid] + red[128 + tid] + red[256 + tid] + red[384 + tid];
  __syncthreads();
  red[wvn * 128 + 2 * l] = b0; red[wvn * 128 + 2 * l + 1] = b1;
  __syncthreads();
  if (tid < 128) {
    float wsv = red[tid] + red[128 + tid] + red[256 + tid] + red[384 + tid];
    ROWBUF[(long)(s - 1) * ldm + n0 + tid] = row;
    OUT[n0 + tid] = wsv + probs[s - 1] * row + CADD[n0 + tid];
  }
}

// ================= prep kernels =================

__global__ __launch_bounds__(NT) void prep1_k(IN in, WS w) {
  long i = (long)blockIdx.x * NT + threadIdx.x;
  const long NG = (long)H3 * H;
  if (i < NG) {
    long n = i / H, k = i - n * H;
    w.Gsum[i] = in.g_wih[n * H3 + H + k] + in.g_wih[n * H3 + 2 * H + k];
  } else if (i < NG + H) {
    int m = (int)(i - NG);
    float a = 0.f;
    for (int t = 0; t < H; t++) a = fmaf(in.bq[t], in.wk[(long)t * H + m], a);
    w.cu[m] = a;
  } else if (i < NG + 2 * H) {
    int m = (int)(i - NG - H);
    float a = 0.f;
    for (int t = 0; t < H; t++) a = fmaf(in.bk[t], in.wq[(long)t * H + m], a);
    w.vkq[m] = a;
  } else if (i == NG + 2 * H) {
    float a = 0.f;
    for (int t = 0; t < H; t++) a = fmaf(in.bk[t], in.bq[t], a);
    w.cb[0] = a;
  }
}

__global__ __launch_bounds__(NT) void prep2_k(IN in, WS w) {
  int i = blockIdx.x * NT + threadIdx.x;
  if (i < H6) {
    const float* row = in.s_wih + (long)i * H2;
    float a = 0.f, c = 0.f;
    for (int t = 0; t < H; t++) { a = fmaf(in.bv[t], row[t], a); c = fmaf(in.attn_h[t], row[t], c); }
    w.cvs[i] = a; w.ch0s[i] = c;
  } else if (i < H6 + H3) {
    int k = i - H6;
    const float* row = in.g_wih + (long)k * H3;
    float a = 0.f, c = 0.f;
    for (int t = 0; t < H; t++) { a = fmaf(in.bv[t], row[t], a); c = fmaf(in.attn_h[t], row[t], c); }
    w.cvg[k] = a; w.chg0[k] = c;
  } else if (i < H6 + H3 + H6) {
    int k = i - H6 - H3;
    const float* row = in.s_whh + (long)k * H2;
    float a = in.s_bhh[k];
    for (int t = 0; t < H2; t++) a = fmaf(in.h0[t], row[t], a);
    w.ghs0[k] = a;
  }
}

// dst[a][n] = (bf16) src[n*rowstride + coloff + a]  ; a<Kd, n<N (both %32==0)
__global__ __launch_bounds__(NT) void transp_k(const float* src, long rowstride, long coloff,
                                               u16* dst, int N, int Kd) {
  __shared__ float t[32][33];
  int a0 = blockIdx.x * 32, n0 = blockIdx.y * 32;
  int tx = threadIdx.x & 31, ty = threadIdx.x >> 5;
  for (int p2 = 0; p2 < 4; p2++) {
    int n = n0 + ty + p2 * 8;
    t[ty + p2 * 8][tx] = src[(long)n * rowstride + coloff + a0 + tx];
  }
  __syncthreads();
  for (int p2 = 0; p2 < 4; p2++) {
    int a = a0 + ty + p2 * 8;
    dst[(long)a * N + n0 + tx] = f2bf(t[tx][ty + p2 * 8]);
  }
}

// ---- generic f32 GEMM: C[M][N] = A[M][K] * B[K][N] (+bias[n]); strided A/B, optional
//      row gather on A; mode1 (C==null): store CT[n][m] as bf16 (ldct). Dims %64==0. ----
__global__ __launch_bounds__(NT) void gemm_k(const float* A, long sAm, long sAk, const int* gather,
                                             const float* B, long sBk, long sBn,
                                             const float* bias,
                                             float* C, u16* CT, long ldct,
                                             int M, int N, int K) {
  __shared__ float As[16][65];
  __shared__ float Bs[16][65];
  __shared__ float Cs[64][65];
  int m0 = blockIdx.y * 64, n0 = blockIdx.x * 64;
  int tid = threadIdx.x;
  int tx = tid & 15, ty = tid >> 4;
  float acc[4][4] = {};
  for (int k0 = 0; k0 < K; k0 += 16) {
    if (sAk == 1) {
      int k = tid & 15, mb = tid >> 4;
      for (int p = 0; p < 4; p++) {
        int m = mb + p * 16;
        long row = gather ? (long)gather[m0 + m] : (long)(m0 + m);
        As[k][m] = A[row * sAm + (k0 + k)];
      }
    } else {
      int m = tid & 63, kb = tid >> 6;
      for (int p = 0; p < 4; p++) {
        int k = kb + p * 4;
        long row = gather ? (long)gather[m0 + m] : (long)(m0 + m);
        As[k][m] = A[row * sAm + (long)(k0 + k) * sAk];
      }
    }
    if (sBn == 1) {
      int n = tid & 63, kb = tid >> 6;
      for (int p = 0; p < 4; p++) {
        int k = kb + p * 4;
        Bs[k][n] = B[(long)(k0 + k) * sBk + (n0 + n)];
      }
    } else {
      int k = tid & 15, nb = tid >> 4;
      for (int p = 0; p < 4; p++) {
        int n = nb + p * 16;
        Bs[k][n] = B[(long)(k0 + k) + (long)(n0 + n) * sBn];
      }
    }
    __syncthreads();
    #pragma unroll
    for (int k = 0; k < 16; k++) {
      float a[4], b[4];
      #pragma unroll
      for (int i = 0; i < 4; i++) a[i] = As[k][ty * 4 + i];
      #pragma unroll
      for (int j = 0; j < 4; j++) b[j] = Bs[k][tx * 4 + j];
      #pragma unroll
      for (int i = 0; i < 4; i++)
        #pragma unroll
        for (int j = 0; j < 4; j++) acc[i][j] = fmaf(a[i], b[j], acc[i][j]);
    }
    __syncthreads();
  }
  if (C) {
    for (int i = 0; i < 4; i++)
      for (int j = 0; j < 4; j++) {
        int m = m0 + ty * 4 + i, n = n0 + tx * 4 + j;
        C[(long)m * N + n] = acc[i][j] + (bias ? bias[n] : 0.f);
      }
  } else {
    for (int i = 0; i < 4; i++)
      for (int j = 0; j < 4; j++)
        Cs[ty * 4 + i][tx * 4 + j] = acc[i][j] + (bias ? bias[n0 + tx * 4 + j] : 0.f);
    __syncthreads();
    int m = tid & 63, nb = tid >> 6;
    for (int p = 0; p < 16; p++) {
      int n = p * 4 + nb;
      CT[(long)(n0 + n) * ldct + (m0 + m)] = f2bf(Cs[m][n]);
    }
  }
}

// ================= sequential kernels =================

__global__ __launch_bounds__(NT) void coop_rnnD(IN in, WS w) {
  __shared__ float h_lds[BB][H];
  __shared__ float red[512];
  int tid = threadIdx.x, wg = blockIdx.x;
  for (int i = tid; i < BB * H; i += NT) ((float*)h_lds)[i] = 0.f;
  __syncthreads();
  int epoch = 1, dead = 0;
  for (int t = 0; t <= SS; t++) {
    if (t > 0) {
      // redundant gates for step t-1 (every WG keeps full h state in LDS)
      for (int idx = tid; idx < BB * H; idx += NT) {
        int b = idx / H, k = idx - b * H;
        long gb = ((long)(b * SS + (t - 1))) * H3;
        const float* gh = w.gh_d + b * H3;
        float r = sigm(w.gi_d[gb + k] + gh[k]);
        float z = sigm(w.gi_d[gb + H + k] + gh[H + k]);
        float n = tanhf(w.gi_d[gb + 2 * H + k] + r * gh[2 * H + k]);
        float hn = (1.f - z) * n + z * h_lds[b][k];
        h_lds[b][k] = hn;
        if (wg == 0) w.dialogue[((long)(b * SS + (t - 1))) * H + k] = hn;
      }
      __syncthreads();
    }
    if (t == SS) break;
    if (t == 0) {
      for (int i = wg * NT + tid; i < BB * H3; i += NWG * NT)
        w.gh_d[i] = in.d_bhh[i % H3];
    } else {
      for (int tau = wg; tau < 144; tau += NWG) {
        int b = tau / 18, n0 = (tau - b * 18) * 128;
        mv128(w.d_whhT, H3, h_lds[b], H, n0, w.gh_d + b * H3, in.d_bhh, red, tid);
      }
    }
    gbar(w.flags1, epoch++, dead);
  }
}

__global__ __launch_bounds__(NT) void coop_main(IN in, WS w) {
  __shared__ float sp_lds[BB][H2];   // per-speaker states (redundant per WG)
  __shared__ float h_lds[H2];
  __shared__ float op_lds[2][H];
  __shared__ float scores_lds[SS];
  __shared__ float probs_lds[SS];
  __shared__ float red[512];
  int tid = threadIdx.x, wg = blockIdx.x;
  for (int i = tid; i < H; i += NT) { op_lds[0][i] = in.d_h0[i]; op_lds[1][i] = 0.f; }
  __syncthreads();
  int epoch = 1, dead = 0;

  for (int g = 0; g <= GG; g++) {
    int s = g & 127, b = g >> 7;
    // ================= PH1 =================
    if (g > 0) {
      // redundant g-GRU gates -> op_{g-1}
      int po = (g - 1) & 1, pn = g & 1;
      const float* GIGr = w.GIG + (long)(g - 1) * H3;
      const float* giw = w.gig_w2 + po * H3;
      const float* ghg = w.gh_g2 + po * H3;
      for (int i = tid; i < H; i += NT) {
        float r = sigm(GIGr[i] + giw[i] + w.gig_h[i] + ghg[i]);
        float z = sigm(GIGr[H + i] + giw[H + i] + w.gig_h[H + i] + ghg[H + i]);
        float n = tanhf(GIGr[2 * H + i] + giw[2 * H + i] + w.gig_h[2 * H + i] + r * ghg[2 * H + i]);
        float opn = (1.f - z) * n + z * op_lds[po][i];
        op_lds[pn][i] = opn;
        if (wg == 0) {
          w.out_op[(long)(g - 1) * H + i] = opn;
          w.op_buf[(long)((g - 1) & 127) * H + i] = opn;
        }
      }
      __syncthreads();
    }
    if (g == GG) break;
    const float* opc = op_lds[g & 1];  // op_{g-1} (d_h0 at g==0)

    // redundant: score for row s-1 + softmax
    if (s >= 1) {
      for (int j = tid; j <= s - 2; j += NT) scores_lds[j] = w.scores_buf[j];
      const float* Ug = w.U + (long)g * H;
      float part = 0.f;
      for (int i = tid; i < H; i += NT) part = fmaf(opc[i], Ug[i], part);
      #pragma unroll
      for (int o = 32; o > 0; o >>= 1) part += __shfl_down(part, o);
      __syncthreads();
      if ((tid & 63) == 0) red[tid >> 6] = part;
      __syncthreads();
      if (tid == 0) {
        scores_lds[s - 1] = red[0] + red[1] + red[2] + red[3] + w.cvec[g];
        scores_lds[s] = w.cvec[g];  // the still-zero op row contributes bk·q only
      }
      __syncthreads();
      float v = (tid <= s) ? scores_lds[tid] : -3.0e38f;
      float m = v;
      #pragma unroll
      for (int o = 32; o > 0; o >>= 1) m = fmaxf(m, __shfl_xor(m, o));
      if ((tid & 63) == 0) red[4 + (tid >> 6)] = m;
      __syncthreads();
      m = fmaxf(fmaxf(red[4], red[5]), fmaxf(red[6], red[7]));
      float e = (tid <= s) ? expf(v - m) : 0.f;
      float su = e;
      #pragma unroll
      for (int o = 32; o > 0; o >>= 1) su += __shfl_xor(su, o);
      if ((tid & 63) == 0) red[8 + (tid >> 6)] = su;
      __syncthreads();
      su = red[8] + red[9] + red[10] + red[11];
      if (tid < SS) probs_lds[tid] = (tid <= s - 1) ? e / su : 0.f;
      __syncthreads();
      if (wg == 0 && tid < SS) w.probs_buf[(long)g * SS + tid] = probs_lds[tid];
    } else {
      if (tid < SS) probs_lds[tid] = 0.f;
      __syncthreads();
      if (wg == 0 && tid < SS) w.probs_buf[(long)g * SS + tid] = 0.f;
    }

    // distributed PH1 tasks
    if (s == 0) {
      for (int tau = wg; tau < 45; tau += NWG) {
        if (tau < 18) { int n0 = tau * 256; w.gi_attn[n0 + tid] = w.ch0s[n0 + tid]; }
        else if (tau < 27) { int n0 = (tau - 18) * 256; w.gig_w2[(g & 1) * H3 + n0 + tid] = w.chg0[n0 + tid]; }
        else mv128(w.g_whhT, H3, opc, H, (tau - 27) * 128, w.gh_g2 + (g & 1) * H3, in.g_bhh, red, tid);
      }
    } else {
      for (int tau = wg; tau < 72; tau += NWG) {
        if (tau < 36)
          wsum_task(w.MsT, H6, opc, w.OPMS, w.gi_attn, w.cvs, probs_lds, s, tau * 128, red, tid);
        else if (tau < 54)
          wsum_task(w.MgT, H3, opc, w.OPMG, w.gig_w2 + (g & 1) * H3, w.cvg, probs_lds, s, (tau - 36) * 128, red, tid);
        else
          mv128(w.g_whhT, H3, opc, H, (tau - 54) * 128, w.gh_g2 + (g & 1) * H3, in.g_bhh, red, tid);
      }
    }
    gbar(w.flags2, epoch++, dead);

    // ================= PH2 =================
    int spk_cur = in.speaker_info[in.chat_ids[b] * SS + s];
    if (s == 0) {
      for (int x = 0; x < BB; x++)
        for (int i = tid; i < H2; i += NT) sp_lds[x][i] = in.h0[i];
    }
    {
      // redundant s-GRU gates -> h_new
      const float* ghs = (s == 0) ? w.ghs0 : (w.gh_s2 + (g & 1) * H6);
      const float* GISr = w.GIS + (long)g * H6;
      for (int i = tid; i < H2; i += NT) {
        float r = sigm(GISr[i] + w.gi_attn[i] + ghs[i]);
        float z = sigm(GISr[H2 + i] + w.gi_attn[H2 + i] + ghs[H2 + i]);
        float n = tanhf(GISr[2 * H2 + i] + w.gi_attn[2 * H2 + i] + r * ghs[2 * H2 + i]);
        float hn = (1.f - z) * n + z * sp_lds[spk_cur][i];
        h_lds[i] = hn;
        sp_lds[spk_cur][i] = hn;
        if (wg == 0) w.h_buf[(long)g * H2 + i] = hn;
      }
      __syncthreads();
    }
    {
      int g1 = g + 1;
      int s1 = g1 & 127;
      int haveNext = (g1 < GG);
      int spk_next = haveNext ? in.speaker_info[in.chat_ids[g1 >> 7] * SS + s1] : 0;
      const float* xnext = sp_lds[spk_next];  // already updated to h_new if same speaker
      int nghs = haveNext ? ((s1 == 0) ? 18 : 36) : 0;
      int nrows = (haveNext && s1 >= 2) ? (s1 - 1) : 0;
      int nsc = (nrows + 31) >> 5;
      int T2 = 18 + nghs + nsc;
      for (int tau = wg; tau < T2; tau += NWG) {
        if (tau < 18)
          mv128(w.g_wihABT, H3, h_lds, H2, tau * 128, w.gig_h, nullptr, red, tid);
        else if (tau < 18 + nghs) {
          int tt = tau - 18;
          if (s1 == 0) { int n0 = tt * 256; w.gh_s2[(g1 & 1) * H6 + n0 + tid] = w.ghs0[n0 + tid]; }
          else mv128(w.s_whhT, H6, xnext, H2, tt * 128, w.gh_s2 + (g1 & 1) * H6, in.s_bhh, red, tid);
        } else {
          int t0 = tau - 18 - nghs;
          int l = tid & 63, wvn = tid >> 6;
          const float* Ug = w.U + (long)g1 * H;
          float cadd = w.cvec[g1];
          for (int q = 0; q < 8; q++) {
            int r = t0 * 32 + wvn * 8 + q;
            if (r >= nrows) break;
            const float* row = w.op_buf + (long)r * H;
            float p = 0.f;
            for (int i = l; i < H; i += 64) p = fmaf(row[i], Ug[i], p);
            #pragma unroll
            for (int o = 32; o > 0; o >>= 1) p += __shfl_down(p, o);
            if (l == 0) w.scores_buf[r] = p + cadd;
          }
        }
      }
    }
    gbar(w.flags2, epoch++, dead);
  }
}

// ================= epilogue =================

__global__ __launch_bounds__(NT) void fixup_u_k(WS w) {
  long i = (long)blockIdx.x * NT + threadIdx.x;
  if (i < (long)GG * H) {
    int m = (int)(i % H);
    w.U[i] = (w.U[i] + w.cu[m]) * INVSCALE;
  }
}

__global__ __launch_bounds__(NT) void cvec_k(WS w) {
  int g = blockIdx.x * 4 + (threadIdx.x >> 6);
  int l = threadIdx.x & 63;
  const float* d = w.dialogue + (long)g * H;
  float p = 0.f;
  for (int i = l; i < H; i += 64) p = fmaf(d[i], w.vkq[i], p);
  #pragma unroll
  for (int o = 32; o > 0; o >>= 1) p += __shfl_down(p, o);
  if (l == 0) w.cvec[g] = (p + w.cb[0]) * INVSCALE;
}

__global__ __launch_bounds__(NT) void epi_W_k(WS w) {
  int g = blockIdx.x, b = g >> 7;
  __shared__ float pl[SS];
  if (threadIdx.x < SS) pl[threadIdx.x] = w.probs_buf[(long)g * SS + threadIdx.x];
  __syncthreads();
  const float* opb = w.out_op + (long)b * SS * H;
  for (int n = threadIdx.x; n < H; n += NT) {
    float acc = 0.f;
    for (int j = 0; j < SS; j++) acc = fmaf(pl[j], opb[(long)j * H + n], acc);
    w.Wbuf[(long)g * H + n] = acc;
  }
}

__global__ __launch_bounds__(NT) void assemble_k(IN in, WS w) {
  long idx = (long)blockIdx.x * NT + threadIdx.x;
  if (idx >= (long)GG * H2) return;
  long g = idx / H2;
  int k = (int)(idx - g * H2);
  int s = (int)(g & 127);
  float t;
  if (k < H) t = (s == 0) ? in.attn_h[k] : w.AO[g * H + k];
  else t = w.dialogue[g * H + (k - H)];
  w.out_spop[idx] = w.h_buf[idx] + t;
}

// ================= host =================

extern "C" void kernel_launch(void* const* d_in, const int* in_sizes, int n_in,
                              void* d_out, int out_size, void* d_ws, size_t ws_size,
                              hipStream_t stream) {
  IN in;
  in.chat_ids = (const int*)d_in[0];
  in.speaker_info = (const int*)d_in[1];
  in.inputs = (const int*)d_in[4];
  in.emb = (const float*)d_in[5];
  in.d_wih = (const float*)d_in[6];  in.d_whh = (const float*)d_in[7];
  in.d_bih = (const float*)d_in[8];  in.d_bhh = (const float*)d_in[9];
  in.g_wih = (const float*)d_in[10]; in.g_whh = (const float*)d_in[11];
  in.g_bih = (const float*)d_in[12]; in.g_bhh = (const float*)d_in[13];
  in.s_wih = (const float*)d_in[14]; in.s_whh = (const float*)d_in[15];
  in.s_bih = (const float*)d_in[16]; in.s_bhh = (const float*)d_in[17];
  in.wq = (const float*)d_in[18];  in.bq = (const float*)d_in[19];
  in.wk = (const float*)d_in[20];  in.bk = (const float*)d_in[21];
  in.wv = (const float*)d_in[22];  in.bv = (const float*)d_in[23];
  in.h0 = (const float*)d_in[24];  in.d_h0 = (const float*)d_in[25];
  in.attn_h = (const float*)d_in[26];

  char* base = (char*)d_ws;
  size_t off = 0;
  auto A = [&](size_t bytes) -> void* {
    size_t r = (off + 255) & ~(size_t)255;
    off = r + bytes;
    return (void*)(base + r);
  };
  WS w;
  w.flags1 = (int*)A(NWG * 4);
  w.flags2 = (int*)A(NWG * 4);
  w.Mqk = (float*)A((size_t)H * H * 4);
  w.Gsum = (float*)A((size_t)H3 * H * 4);
  w.cu = (float*)A(H * 4);
  w.vkq = (float*)A(H * 4);
  w.cb = (float*)A(4);
  w.cvs = (float*)A(H6 * 4);
  w.ch0s = (float*)A(H6 * 4);
  w.cvg = (float*)A(H3 * 4);
  w.chg0 = (float*)A(H3 * 4);
  w.ghs0 = (float*)A(H6 * 4);
  w.MsT = (u16*)A((size_t)H * H6 * 2);
  w.MgT = (u16*)A((size_t)H * H3 * 2);
  w.s_whhT = (u16*)A((size_t)H2 * H6 * 2);
  w.g_whhT = (u16*)A((size_t)H * H3 * 2);
  w.g_wihABT = (u16*)A((size_t)H2 * H3 * 2);
  w.d_whhT = (u16*)A((size_t)H * H3 * 2);
  {
    void* r1 = A((size_t)GG * H6 * 4);  // max(gi_d [GG*H3], GIS [GG*H6])
    w.gi_d = (float*)r1;
    w.GIS = (float*)r1;
  }
  w.dialogue = (float*)A((size_t)GG * H * 4);
  w.U = (float*)A((size_t)GG * H * 4);
  w.cvec = (float*)A(GG * 4);
  w.GIG = (float*)A((size_t)GG * H3 * 4);
  w.gh_d = (float*)A((size_t)BB * H3 * 4);
  w.op_buf = (float*)A((size_t)SS * H * 4);
  w.OPMS = (float*)A((size_t)SS * H6 * 4);
  w.OPMG = (float*)A((size_t)SS * H3 * 4);
  w.gi_attn = (float*)A(H6 * 4);
  w.gh_s2 = (float*)A(2 * H6 * 4);
  w.gh_g2 = (float*)A(2 * H3 * 4);
  w.gig_w2 = (float*)A(2 * H3 * 4);
  w.gig_h = (float*)A(H3 * 4);
  w.scores_buf = (float*)A(SS * 4);
  w.probs_buf = (float*)A((size_t)GG * SS * 4);
  w.h_buf = (float*)A((size_t)GG * H2 * 4);
  w.Wbuf = (float*)A((size_t)GG * H * 4);
  w.AO = (float*)A((size_t)GG * H * 4);
  w.out_op = (float*)d_out;
  w.out_spop = (float*)d_out + (size_t)GG * H;

  hipMemsetAsync(w.flags1, 0, NWG * 4, stream);
  hipMemsetAsync(w.flags2, 0, NWG * 4, stream);

  const long NG = (long)H3 * H;
  prep1_k<<<(int)((NG + 2 * H + 1 + NT - 1) / NT), NT, 0, stream>>>(in, w);
  prep2_k<<<(H6 + H3 + H6 + NT - 1) / NT, NT, 0, stream>>>(in, w);

  transp_k<<<dim3(H2 / 32, H6 / 32), NT, 0, stream>>>(in.s_whh, H2, 0, w.s_whhT, H6, H2);
  transp_k<<<dim3(H / 32, H3 / 32), NT, 0, stream>>>(in.g_whh, H, 0, w.g_whhT, H3, H);
  transp_k<<<dim3(H2 / 32, H3 / 32), NT, 0, stream>>>(in.g_wih, H3, 0, w.g_wihABT, H3, H2);
  transp_k<<<dim3(H / 32, H3 / 32), NT, 0, stream>>>(in.d_whh, H, 0, w.d_whhT, H3, H);

  // Mqk = wq^T @ wk
  gemm_k<<<dim3(H / 64, H / 64), NT, 0, stream>>>(in.wq, 1, H, nullptr, in.wk, H, 1, nullptr,
                                                  w.Mqk, nullptr, 0, H, H, H);
  // MsT (bf16, transposed) = (s_wihA @ wv)^T
  gemm_k<<<dim3(H / 64, H6 / 64), NT, 0, stream>>>(in.s_wih, H2, 1, nullptr, in.wv, H, 1, nullptr,
                                                   nullptr, w.MsT, H6, H6, H, H);
  // MgT = (g_wihA @ wv)^T
  gemm_k<<<dim3(H / 64, H3 / 64), NT, 0, stream>>>(in.g_wih, H3, 1, nullptr, in.wv, H, 1, nullptr,
                                                   nullptr, w.MgT, H3, H3, H, H);
  // gi_d = emb[inputs] @ d_wih^T + d_bih
  gemm_k<<<dim3(H3 / 64, GG / 64), NT, 0, stream>>>(in.emb, H, 1, in.inputs, in.d_wih, 1, H,
                                                    in.d_bih, w.gi_d, nullptr, 0, GG, H3, H);
  coop_rnnD<<<NWG, NT, 0, stream>>>(in, w);

  // U = dialogue @ Mqk   (then +cu, *1/scale)
  gemm_k<<<dim3(H / 64, GG / 64), NT, 0, stream>>>(w.dialogue, H, 1, nullptr, w.Mqk, H, 1, nullptr,
                                                   w.U, nullptr, 0, GG, H, H);
  // GIS = dialogue @ s_wihB^T + s_bih
  gemm_k<<<dim3(H6 / 64, GG / 64), NT, 0, stream>>>(w.dialogue, H, 1, nullptr, in.s_wih + H, 1, H2,
                                                    in.s_bih, w.GIS, nullptr, 0, GG, H6, H);
  // GIG = dialogue @ Gsum^T + g_bih
  gemm_k<<<dim3(H3 / 64, GG / 64), NT, 0, stream>>>(w.dialogue, H, 1, nullptr, w.Gsum, 1, H,
                                                    in.g_bih, w.GIG, nullptr, 0, GG, H3, H);
  fixup_u_k<<<(GG * H + NT - 1) / NT, NT, 0, stream>>>(w);
  cvec_k<<<GG / 4, NT, 0, stream>>>(w);

  coop_main<<<NWG, NT, 0, stream>>>(in, w);

  epi_W_k<<<GG, NT, 0, stream>>>(w);
  // AO = Wbuf @ wv^T + bv
  gemm_k<<<dim3(H / 64, GG / 64), NT, 0, stream>>>(w.Wbuf, H, 1, nullptr, in.wv, 1, H,
                                                   in.bv, w.AO, nullptr, 0, GG, H, H);
  assemble_k<<<(int)(((long)GG * H2 + NT - 1) / NT), NT, 0, stream>>>(in, w);
}